// Round 7
// baseline (476.777 us; speedup 1.0000x reference)
//
#include <hip/hip_runtime.h>
#include <hip/hip_bf16.h>
#include <stdint.h>

#define B_  4
#define T_  8192
#define H_  1024
#define NH_ 16
#define D_  64
#define BT_ (B_*T_)

typedef __attribute__((ext_vector_type(8))) __bf16 bf16x8;
typedef __attribute__((ext_vector_type(4))) __bf16 bf16x4;
typedef __attribute__((ext_vector_type(4))) float  f32x4;

template<int N> struct IC { static constexpr int v = N; };

__device__ __forceinline__ float phi_f(float x) {
    return x > 0.0f ? x + 1.0f : __expf(x);
}

__device__ __forceinline__ void async_copy16(const void* g, void* l) {
    __builtin_amdgcn_global_load_lds(
        (const __attribute__((address_space(1))) uint32_t*)g,
        (__attribute__((address_space(3))) uint32_t*)l, 16, 0, 0);
}

// ---------------------------------------------------------------------------
// fp32 -> bf16 conversion, 8 elems/thread
// ---------------------------------------------------------------------------
__global__ void conv_bf16(const float* __restrict__ src, __bf16* __restrict__ dst) {
    size_t i = ((size_t)blockIdx.x * 256 + threadIdx.x) * 8;
    float4 a = *(const float4*)(src + i);
    float4 b = *(const float4*)(src + i + 4);
    bf16x8 o;
    o[0]=(__bf16)a.x; o[1]=(__bf16)a.y; o[2]=(__bf16)a.z; o[3]=(__bf16)a.w;
    o[4]=(__bf16)b.x; o[5]=(__bf16)b.y; o[6]=(__bf16)b.z; o[7]=(__bf16)b.w;
    *(bf16x8*)(dst + i) = o;
}

__global__ void wconv4(const float* __restrict__ s0, const float* __restrict__ s1,
                       const float* __restrict__ s2, const float* __restrict__ s3,
                       __bf16* __restrict__ d0, __bf16* __restrict__ d1,
                       __bf16* __restrict__ d2, __bf16* __restrict__ d3) {
    const float* s; __bf16* d;
    switch (blockIdx.y) {
        case 0: s = s0; d = d0; break;
        case 1: s = s1; d = d1; break;
        case 2: s = s2; d = d2; break;
        default: s = s3; d = d3; break;
    }
    int i = (blockIdx.x * 256 + threadIdx.x) * 4;
    float4 v = *(const float4*)(s + i);
    bf16x4 o;
    o[0] = (__bf16)v.x; o[1] = (__bf16)v.y; o[2] = (__bf16)v.z; o[3] = (__bf16)v.w;
    *(bf16x4*)(d + i) = o;
}

// ---------------------------------------------------------------------------
// 256x256 GEMM, 8-phase counted-vmcnt schedule (T2+T3+T4+T5).
// Identical sync structure to round 6; buffer parity is now COMPILE-TIME
// (generic lambda + pairwise unroll) so LDS addresses fold to immediates.
// ---------------------------------------------------------------------------
template<int EPI>
__global__ __launch_bounds__(512, 2)
void gemm_bt(const __bf16* __restrict__ A, const __bf16* __restrict__ Wb,
             const float* __restrict__ mask, void* __restrict__ OutV)
{
    __shared__ __align__(16) char lds[131072];

    const int orig = blockIdx.x;
    const int wg = (orig & 7) * 64 + (orig >> 3);   // 512 wgs, bijective XCD swz
    const int bm = (wg >> 2) * 256;
    const int bn = (wg & 3) * 256;
    const int tid = threadIdx.x;
    const int lane = tid & 63;
    const int w = tid >> 6;
    const int wm = w >> 2, wn = w & 3;
    const int lane15 = lane & 15;
    const int k16 = (lane >> 4) * 16;
    const int rswz = (lane & 7) << 4;

    // staging: thread covers row n = r*64 + w*8 + (lane>>3), byte (lane&7)*16,
    // source pre-swizzled so XOR-swizzled reads are conflict-free.
    const int csw  = ((lane & 7) << 4) ^ ((lane >> 3) << 4);
    const int nrow = w * 8 + (lane >> 3);
    const int udst = w * 1024;               // + r*8192 (+lane*16 by HW)

    const char* gA[2][2];
    const char* gB[2][2];
    #pragma unroll
    for (int h = 0; h < 2; ++h)
        #pragma unroll
        for (int r = 0; r < 2; ++r) {
            gA[h][r] = (const char*)(A  + (size_t)(bm + h*128 + r*64 + nrow) * H_) + csw;
            gB[h][r] = (const char*)(Wb + (size_t)(bn + h*128 + r*64 + nrow) * H_) + csw;
        }

    auto STAGE_A = [&](auto dbc, int kt) {
        constexpr int DB = decltype(dbc)::v;
        const int kb = kt * 128;
        char* d = (char*)lds + DB * 65536 + udst;
        async_copy16(gA[0][0] + kb, d);
        async_copy16(gA[0][1] + kb, d + 8192);
        async_copy16(gA[1][0] + kb, d + 16384);
        async_copy16(gA[1][1] + kb, d + 24576);
    };
    auto STAGE_B = [&](auto dbc, int kt) {
        constexpr int DB = decltype(dbc)::v;
        const int kb = kt * 128;
        char* d = (char*)lds + DB * 65536 + 32768 + udst;
        async_copy16(gB[0][0] + kb, d);
        async_copy16(gB[0][1] + kb, d + 8192);
        async_copy16(gB[1][0] + kb, d + 16384);
        async_copy16(gB[1][1] + kb, d + 24576);
    };

    f32x4 acc[8][4];
    #pragma unroll
    for (int i = 0; i < 8; ++i)
        #pragma unroll
        for (int j = 0; j < 4; ++j) acc[i][j] = (f32x4)0.0f;

    bf16x8 aF[4][2], bF[4][2];
    const int abase = wm * 16384;                                  // wave's A-half
    const int bbase = 32768 + (wn >> 1) * 16384 + (wn & 1) * 8192; // wave's B strip

    // kt_body: 4 phases, each {ds_read frags; [stage]; barrier; setprio(1);
    // 16 MFMA (one C-quadrant); setprio(0); barrier}.  vmcnt(8) once per
    // K-tile at p3 (retires kt+1's 8 loads, leaves kt+2's 8 in flight).
    auto kt_body = [&](auto dbc, int kt, int do_stage, int waitk) {
        constexpr int DB = decltype(dbc)::v;
        const char* pa = (const char*)lds + DB * 65536 + abase;
        const char* pb = (const char*)lds + DB * 65536 + bbase;
        // ---- p0: M0-3 x N0-1 ----
        #pragma unroll
        for (int m = 0; m < 4; ++m)
            #pragma unroll
            for (int ks = 0; ks < 2; ++ks)
                aF[m][ks] = *(const bf16x8*)(pa + (m*16 + lane15)*128 + ((ks*64 + k16) ^ rswz));
        #pragma unroll
        for (int n = 0; n < 2; ++n)
            #pragma unroll
            for (int ks = 0; ks < 2; ++ks)
                bF[n][ks] = *(const bf16x8*)(pb + (n*16 + lane15)*128 + ((ks*64 + k16) ^ rswz));
        __builtin_amdgcn_s_barrier();
        __builtin_amdgcn_s_setprio(1);
        #pragma unroll
        for (int m = 0; m < 4; ++m)
            #pragma unroll
            for (int n = 0; n < 2; ++n) {
                acc[m][n] = __builtin_amdgcn_mfma_f32_16x16x32_bf16(aF[m][0], bF[n][0], acc[m][n], 0, 0, 0);
                acc[m][n] = __builtin_amdgcn_mfma_f32_16x16x32_bf16(aF[m][1], bF[n][1], acc[m][n], 0, 0, 0);
            }
        __builtin_amdgcn_s_setprio(0);
        __builtin_amdgcn_s_barrier();
        // ---- p1: M0-3 x N2-3 ----
        #pragma unroll
        for (int n = 2; n < 4; ++n)
            #pragma unroll
            for (int ks = 0; ks < 2; ++ks)
                bF[n][ks] = *(const bf16x8*)(pb + (n*16 + lane15)*128 + ((ks*64 + k16) ^ rswz));
        __builtin_amdgcn_s_barrier();
        __builtin_amdgcn_s_setprio(1);
        #pragma unroll
        for (int m = 0; m < 4; ++m)
            #pragma unroll
            for (int n = 2; n < 4; ++n) {
                acc[m][n] = __builtin_amdgcn_mfma_f32_16x16x32_bf16(aF[m][0], bF[n][0], acc[m][n], 0, 0, 0);
                acc[m][n] = __builtin_amdgcn_mfma_f32_16x16x32_bf16(aF[m][1], bF[n][1], acc[m][n], 0, 0, 0);
            }
        __builtin_amdgcn_s_setprio(0);
        __builtin_amdgcn_s_barrier();
        // ---- p2: M4-7 x N0-1 (stage B of kt+2 into freed B slots) ----
        #pragma unroll
        for (int m = 0; m < 4; ++m)
            #pragma unroll
            for (int ks = 0; ks < 2; ++ks)
                aF[m][ks] = *(const bf16x8*)(pa + ((m+4)*16 + lane15)*128 + ((ks*64 + k16) ^ rswz));
        if (do_stage) STAGE_B(dbc, kt + 2);
        __builtin_amdgcn_s_barrier();
        __builtin_amdgcn_s_setprio(1);
        #pragma unroll
        for (int m = 0; m < 4; ++m)
            #pragma unroll
            for (int n = 0; n < 2; ++n) {
                acc[m+4][n] = __builtin_amdgcn_mfma_f32_16x16x32_bf16(aF[m][0], bF[n][0], acc[m+4][n], 0, 0, 0);
                acc[m+4][n] = __builtin_amdgcn_mfma_f32_16x16x32_bf16(aF[m][1], bF[n][1], acc[m+4][n], 0, 0, 0);
            }
        __builtin_amdgcn_s_setprio(0);
        __builtin_amdgcn_s_barrier();
        // ---- p3: M4-7 x N2-3 (stage A of kt+2; counted wait) ----
        if (do_stage) STAGE_A(dbc, kt + 2);
        if (waitk == 1)      asm volatile("s_waitcnt vmcnt(8)" ::: "memory");
        else if (waitk == 2) asm volatile("s_waitcnt vmcnt(0)" ::: "memory");
        __builtin_amdgcn_s_barrier();
        __builtin_amdgcn_s_setprio(1);
        #pragma unroll
        for (int m = 0; m < 4; ++m)
            #pragma unroll
            for (int n = 2; n < 4; ++n) {
                acc[m+4][n] = __builtin_amdgcn_mfma_f32_16x16x32_bf16(aF[m][0], bF[n][0], acc[m+4][n], 0, 0, 0);
                acc[m+4][n] = __builtin_amdgcn_mfma_f32_16x16x32_bf16(aF[m][1], bF[n][1], acc[m+4][n], 0, 0, 0);
            }
        __builtin_amdgcn_s_setprio(0);
        __builtin_amdgcn_s_barrier();
    };

    // prologue: stage kt0, kt1; retire kt0's 8 (kt1's 8 stay in flight)
    STAGE_B(IC<0>{}, 0); STAGE_A(IC<0>{}, 0);
    STAGE_B(IC<1>{}, 1); STAGE_A(IC<1>{}, 1);
    asm volatile("s_waitcnt vmcnt(8)" ::: "memory");
    __builtin_amdgcn_s_barrier();

    #pragma unroll 1
    for (int kt = 0; kt < 12; kt += 2) {
        kt_body(IC<0>{}, kt,     1, 1);
        kt_body(IC<1>{}, kt + 1, 1, 1);
    }
    kt_body(IC<0>{}, 12, 1, 1);
    kt_body(IC<1>{}, 13, 1, 1);
    kt_body(IC<0>{}, 14, 0, 2);
    kt_body(IC<1>{}, 15, 0, 0);

    // epilogue: C row = (lane>>4)*4 + j, col = lane&15
    const int gm0 = bm + wm * 128;
    const int gn0 = bn + wn * 64 + lane15;
    #pragma unroll
    for (int mi = 0; mi < 8; ++mi) {
        #pragma unroll
        for (int j = 0; j < 4; ++j) {
            int gm = gm0 + mi * 16 + (lane >> 4) * 4 + j;
            if (EPI == 3) {
                float* op = (float*)OutV + (size_t)gm * H_ + gn0;
                #pragma unroll
                for (int ni = 0; ni < 4; ++ni)
                    op[ni * 16] = acc[mi][ni][j];
            } else {
                float mv = (EPI >= 1) ? mask[gm] : 1.0f;
                __bf16* op = (__bf16*)OutV + (size_t)gm * H_ + gn0;
                #pragma unroll
                for (int ni = 0; ni < 4; ++ni) {
                    float v = acc[mi][ni][j];
                    if (EPI == 0)      v = phi_f(v);
                    else if (EPI == 1) v = phi_f(v) * mv;
                    else               v = v * mv;
                    op[ni * 16] = (__bf16)v;
                }
            }
        }
    }
}

// ---------------------------------------------------------------------------
// KV partials via MFMA (unchanged, passing)
// ---------------------------------------------------------------------------
__global__ __launch_bounds__(256, 2)
void kv_kernel(const __bf16* __restrict__ Kb, const __bf16* __restrict__ Vb,
               float* __restrict__ KVp, float* __restrict__ Ksp)
{
    const int chunk = blockIdx.x;
    const int bh = blockIdx.y;
    const int b = bh >> 4, h = bh & 15;
    const int tid = threadIdx.x, lane = tid & 63, wid = tid >> 6;

    __shared__ char KtRaw[64 * 144];
    __shared__ char VtRaw[64 * 144];
    __shared__ float ksbuf[32][64];

    const int st  = tid >> 3;
    const int dkg = tid & 7;
    const int dk0 = dkg * 8;
    const int swzT = (dkg & 7) << 4;

    f32x4 acc[4];
    #pragma unroll
    for (int i = 0; i < 4; ++i) acc[i] = (f32x4)0.0f;
    float ksacc[8];
    #pragma unroll
    for (int i = 0; i < 8; ++i) ksacc[i] = 0.0f;

    const size_t gbase = ((size_t)b * T_ + (size_t)chunk * 1024) * H_
                         + h * 64 + dk0;

    bf16x8 ka, kc, va, vc;
    {
        const __bf16* p  = Kb + gbase;
        const __bf16* pv = Vb + gbase;
        ka = *(const bf16x8*)(p  + (size_t)st * H_);
        kc = *(const bf16x8*)(p  + (size_t)(st + 32) * H_);
        va = *(const bf16x8*)(pv + (size_t)st * H_);
        vc = *(const bf16x8*)(pv + (size_t)(st + 32) * H_);
    }

    for (int tile = 0; tile < 16; ++tile) {
        __syncthreads();
        #pragma unroll
        for (int j = 0; j < 8; ++j) {
            int rowb = (dk0 + j) * 144;
            *(__bf16*)(KtRaw + ((rowb + 2*st)        ^ swzT)) = ka[j];
            *(__bf16*)(KtRaw + ((rowb + 2*(st + 32)) ^ swzT)) = kc[j];
            *(__bf16*)(VtRaw + ((rowb + 2*st)        ^ swzT)) = va[j];
            *(__bf16*)(VtRaw + ((rowb + 2*(st + 32)) ^ swzT)) = vc[j];
            ksacc[j] += (float)ka[j] + (float)kc[j];
        }
        if (tile < 15) {
            const __bf16* p  = Kb + gbase + (size_t)(tile + 1) * 64 * H_;
            const __bf16* pv = Vb + gbase + (size_t)(tile + 1) * 64 * H_;
            ka = *(const bf16x8*)(p  + (size_t)st * H_);
            kc = *(const bf16x8*)(p  + (size_t)(st + 32) * H_);
            va = *(const bf16x8*)(pv + (size_t)st * H_);
            vc = *(const bf16x8*)(pv + (size_t)(st + 32) * H_);
        }
        __syncthreads();
        #pragma unroll
        for (int ks = 0; ks < 2; ++ks) {
            int r = wid * 16 + (lane & 15);
            int cb = (r * 144 + (ks * 64 + (lane >> 4) * 16)) ^ (((r >> 3) & 7) << 4);
            bf16x8 af = *(const bf16x8*)(KtRaw + cb);
            #pragma unroll
            for (int ni = 0; ni < 4; ++ni) {
                int rv = ni * 16 + (lane & 15);
                int cv = (rv * 144 + (ks * 64 + (lane >> 4) * 16)) ^ (((rv >> 3) & 7) << 4);
                bf16x8 bf = *(const bf16x8*)(VtRaw + cv);
                acc[ni] = __builtin_amdgcn_mfma_f32_16x16x32_bf16(af, bf, acc[ni], 0, 0, 0);
            }
        }
    }

    float* kvp = KVp + ((size_t)chunk * 64 + bh) * 4096;
    #pragma unroll
    for (int ni = 0; ni < 4; ++ni)
        #pragma unroll
        for (int jj = 0; jj < 4; ++jj) {
            int dk = wid * 16 + (lane >> 4) * 4 + jj;
            int dv = ni * 16 + (lane & 15);
            kvp[dk * 64 + dv] = acc[ni][jj];
        }

    #pragma unroll
    for (int j = 0; j < 8; ++j)
        ksbuf[st][dk0 + j] = ksacc[j];
    __syncthreads();
    if (tid < 64) {
        float s = 0.0f;
        #pragma unroll 8
        for (int st2 = 0; st2 < 32; ++st2) s += ksbuf[st2][tid];
        Ksp[((size_t)chunk * 64 + bh) * 64 + tid] = s;
    }
}

__global__ void kvt_kernel(const float* __restrict__ KVp, const float* __restrict__ Ksp,
                           __bf16* __restrict__ KVT, float* __restrict__ Ks) {
    int bh = blockIdx.x, tid = threadIdx.x;
    __bf16* d = KVT + (size_t)bh * 4096;
    for (int i = tid; i < 4096; i += 256) {
        float s = 0.0f;
        #pragma unroll
        for (int c = 0; c < 8; ++c)
            s += KVp[((size_t)c * 64 + bh) * 4096 + i];
        int dk = i >> 6, dv = i & 63;
        d[dv * 64 + dk] = (__bf16)s;
    }
    if (tid < 64) {
        float s = 0.0f;
        #pragma unroll
        for (int c = 0; c < 8; ++c)
            s += Ksp[((size_t)c * 64 + bh) * 64 + tid];
        Ks[bh * 64 + tid] = s;
    }
}

// ---------------------------------------------------------------------------
// attn (unchanged, passing)
// ---------------------------------------------------------------------------
__global__ __launch_bounds__(256, 2)
void attn_kernel(const __bf16* __restrict__ Qb, const __bf16* __restrict__ KVT,
                 const float* __restrict__ Ksum, __bf16* __restrict__ On)
{
    const int bh = blockIdx.y;
    const int b = bh >> 4, h = bh & 15;
    const int tc = blockIdx.x;
    const int tid = threadIdx.x, lane = tid & 63, wid = tid >> 6;
    __shared__ __bf16 kvl[64][72];
    __shared__ float dinv[256];

    {
        const int r = tid >> 2, part = tid & 3;
        const __bf16* src = KVT + (size_t)bh * 4096 + r * 64 + part * 16;
        *(bf16x8*)&kvl[r][part*16]     = *(const bf16x8*)src;
        *(bf16x8*)&kvl[r][part*16 + 8] = *(const bf16x8*)(src + 8);
    }
    {
        const int t = tc * 256 + tid;
        const __bf16* qp = Qb + ((size_t)b * T_ + t) * H_ + h * 64;
        const float* kp = Ksum + bh * 64;
        float s = 0.0f;
        #pragma unroll
        for (int i = 0; i < 8; ++i) {
            bf16x8 qv = *(const bf16x8*)(qp + i * 8);
            #pragma unroll
            for (int j = 0; j < 8; ++j) s += (float)qv[j] * kp[i*8 + j];
        }
        dinv[tid] = 1.0f / (s + 1e-6f);
    }
    __syncthreads();

    f32x4 acc[4][4];
    #pragma unroll
    for (int i = 0; i < 4; ++i)
        #pragma unroll
        for (int j = 0; j < 4; ++j) acc[i][j] = (f32x4)0.0f;

    const int t0 = tc * 256 + wid * 64;
    #pragma unroll
    for (int ks = 0; ks < 2; ++ks) {
        bf16x8 afr[4], bfr[4];
        #pragma unroll
        for (int mi = 0; mi < 4; ++mi) {
            int t = t0 + mi * 16 + (lane & 15);
            afr[mi] = *(const bf16x8*)(Qb + ((size_t)b * T_ + t) * H_ + h * 64
                                       + ks * 32 + (lane >> 4) * 8);
        }
        #pragma unroll
        for (int ni = 0; ni < 4; ++ni) {
            int dv = ni * 16 + (lane & 15);
            bfr[ni] = *(const bf16x8*)&kvl[dv][ks * 32 + (lane >> 4) * 8];
        }
        #pragma unroll
        for (int mi = 0; mi < 4; ++mi)
            #pragma unroll
            for (int ni = 0; ni < 4; ++ni)
                acc[mi][ni] = __builtin_amdgcn_mfma_f32_16x16x32_bf16(
                    afr[mi], bfr[ni], acc[mi][ni], 0, 0, 0);
    }
    #pragma unroll
    for (int mi = 0; mi < 4; ++mi)
        #pragma unroll
        for (int j = 0; j < 4; ++j) {
            int lt = wid * 64 + mi * 16 + (lane >> 4) * 4 + j;
            float z = dinv[lt];
            int t = tc * 256 + lt;
            __bf16* op = On + ((size_t)b * T_ + t) * H_ + h * 64 + (lane & 15);
            #pragma unroll
            for (int ni = 0; ni < 4; ++ni)
                op[ni * 16] = (__bf16)(acc[mi][ni][j] * z);
        }
}

// ---------------------------------------------------------------------------
extern "C" void kernel_launch(void* const* d_in, const int* in_sizes, int n_in,
                              void* d_out, int out_size, void* d_ws, size_t ws_size,
                              hipStream_t stream) {
    (void)in_sizes; (void)n_in; (void)out_size; (void)ws_size;
    const float* q    = (const float*)d_in[0];
    const float* k    = (const float*)d_in[1];
    const float* v    = (const float*)d_in[2];
    const float* mask = (const float*)d_in[3];
    const float* Wq   = (const float*)d_in[4];
    const float* Wk   = (const float*)d_in[5];
    const float* Wv   = (const float*)d_in[6];
    const float* Wo   = (const float*)d_in[7];
    float* out = (float*)d_out;

    char* ws = (char*)d_ws;
    const size_t WELEM = (size_t)H_ * H_;
    const size_t PELEM = (size_t)BT_ * H_;
    __bf16* Wqb = (__bf16*)ws;
    __bf16* Wkb = Wqb + WELEM;
    __bf16* Wvb = Wkb + WELEM;
    __bf16* Wob = Wvb + WELEM;
    __bf16* Qb  = Wob + WELEM;
    __bf16* Kb  = Qb + PELEM;
    __bf16* Vb  = Kb + PELEM;
    __bf16* tmp = Vb + PELEM;                 // conv buffer, later attn out
    float*  KVp = (float*)(tmp + PELEM);
    float*  Ksp = KVp + (size_t)8 * 64 * 4096;
    float*  Ksf = Ksp + (size_t)8 * 64 * 64;
    __bf16* KVT = (__bf16*)(Ksf + (size_t)64 * 64);

    wconv4<<<dim3(1024, 4), 256, 0, stream>>>(Wq, Wk, Wv, Wo, Wqb, Wkb, Wvb, Wob);

    const int cgrid = (int)(PELEM / (256 * 8));
    const int ggrid = (BT_ / 256) * (H_ / 256);   // 512
    conv_bf16<<<cgrid, 256, 0, stream>>>(q, tmp);
    gemm_bt<0><<<ggrid, 512, 0, stream>>>(tmp, Wqb, mask, Qb);
    conv_bf16<<<cgrid, 256, 0, stream>>>(k, tmp);
    gemm_bt<1><<<ggrid, 512, 0, stream>>>(tmp, Wkb, mask, Kb);
    conv_bf16<<<cgrid, 256, 0, stream>>>(v, tmp);
    gemm_bt<2><<<ggrid, 512, 0, stream>>>(tmp, Wvb, mask, Vb);

    kv_kernel<<<dim3(T_/1024, B_*NH_), 256, 0, stream>>>(Kb, Vb, KVp, Ksp);
    kvt_kernel<<<B_*NH_, 256, 0, stream>>>(KVp, Ksp, KVT, Ksf);
    attn_kernel<<<dim3(T_/256, B_*NH_), 256, 0, stream>>>(Qb, KVT, Ksf, tmp);
    gemm_bt<3><<<ggrid, 512, 0, stream>>>(tmp, Wob, mask, out);
}

// Round 8
// 431.672 us; speedup vs baseline: 1.1045x; 1.1045x over previous
//
#include <hip/hip_runtime.h>
#include <hip/hip_bf16.h>
#include <stdint.h>

#define B_  4
#define T_  8192
#define H_  1024
#define NH_ 16
#define D_  64
#define BT_ (B_*T_)

typedef __attribute__((ext_vector_type(8))) __bf16 bf16x8;
typedef __attribute__((ext_vector_type(4))) __bf16 bf16x4;
typedef __attribute__((ext_vector_type(4))) float  f32x4;

__device__ __forceinline__ float phi_f(float x) {
    return x > 0.0f ? x + 1.0f : __expf(x);
}

__device__ __forceinline__ void async_copy16(const void* g, void* l) {
    __builtin_amdgcn_global_load_lds(
        (const __attribute__((address_space(1))) uint32_t*)g,
        (__attribute__((address_space(3))) uint32_t*)l, 16, 0, 0);
}

// ---------------------------------------------------------------------------
// fp32 -> bf16 conversion, 8 elems/thread
// ---------------------------------------------------------------------------
__global__ void conv_bf16(const float* __restrict__ src, __bf16* __restrict__ dst) {
    size_t i = ((size_t)blockIdx.x * 256 + threadIdx.x) * 8;
    float4 a = *(const float4*)(src + i);
    float4 b = *(const float4*)(src + i + 4);
    bf16x8 o;
    o[0]=(__bf16)a.x; o[1]=(__bf16)a.y; o[2]=(__bf16)a.z; o[3]=(__bf16)a.w;
    o[4]=(__bf16)b.x; o[5]=(__bf16)b.y; o[6]=(__bf16)b.z; o[7]=(__bf16)b.w;
    *(bf16x8*)(dst + i) = o;
}

__global__ void wconv4(const float* __restrict__ s0, const float* __restrict__ s1,
                       const float* __restrict__ s2, const float* __restrict__ s3,
                       __bf16* __restrict__ d0, __bf16* __restrict__ d1,
                       __bf16* __restrict__ d2, __bf16* __restrict__ d3) {
    const float* s; __bf16* d;
    switch (blockIdx.y) {
        case 0: s = s0; d = d0; break;
        case 1: s = s1; d = d1; break;
        case 2: s = s2; d = d2; break;
        default: s = s3; d = d3; break;
    }
    int i = (blockIdx.x * 256 + threadIdx.x) * 4;
    float4 v = *(const float4*)(s + i);
    bf16x4 o;
    o[0] = (__bf16)v.x; o[1] = (__bf16)v.y; o[2] = (__bf16)v.z; o[3] = (__bf16)v.w;
    *(bf16x4*)(d + i) = o;
}

// ---------------------------------------------------------------------------
// 128x128 GEMM (round-4 structure, 904 TF): Out = epi(A @ W^T), both bf16 via
// global_load_lds (pre-swizzled source -> XOR-swizzled conflict-free reads).
// EPI: 0 = Q' = z*phi  -> bf16  (z = 1/(phi(Q).Ksum + 1e-6); aux = Ksum)
//      1 = phi*mask    -> bf16  (K)
//      2 = mask        -> bf16  (V)
//      3 = none        -> fp32  (final; W is per-batch: Wb + (bm>>13)<<20)
// ---------------------------------------------------------------------------
template<int EPI>
__global__ __launch_bounds__(256, 2)
void gemm_bt(const __bf16* __restrict__ A, const __bf16* __restrict__ Wb,
             const float* __restrict__ mask, const float* __restrict__ aux,
             void* __restrict__ OutV)
{
    const int orig = blockIdx.x;
    const int wgid = (orig & 7) * 256 + (orig >> 3);   // nwg=2048, %8==0: bijective
    const int bm = (wgid >> 3) * 128;
    const int bn = (wgid & 7) * 128;
    const int tid  = threadIdx.x;
    const int lane = tid & 63;
    const int wid  = tid >> 6;
    const int wm = wid >> 1, wn = wid & 1;

    const __bf16* Wp = Wb;
    if (EPI == 3) Wp = Wb + ((size_t)(bm >> 13) << 20);   // per-batch U

    __shared__ __bf16 Al[128 * 64];
    __shared__ __bf16 Bl[128 * 64];

    f32x4 acc[4][4];
    #pragma unroll
    for (int i = 0; i < 4; ++i)
        #pragma unroll
        for (int j = 0; j < 4; ++j) acc[i][j] = (f32x4)0.0f;

    const int sn = wid * 8 + (lane >> 3);
    const int sc = (lane & 7) * 16;

    for (int k0 = 0; k0 < H_; k0 += 64) {
        #pragma unroll
        for (int issue = 0; issue < 4; ++issue) {
            int n = issue * 32 + sn;
            int csw = sc ^ ((n & 7) << 4);
            async_copy16((const char*)(A  + (size_t)(bm + n) * H_ + k0) + csw,
                         (char*)Al + issue * 4096 + wid * 1024);
            async_copy16((const char*)(Wp + (size_t)(bn + n) * H_ + k0) + csw,
                         (char*)Bl + issue * 4096 + wid * 1024);
        }
        __syncthreads();
        #pragma unroll
        for (int ks = 0; ks < 2; ++ks) {
            bf16x8 afr[4], bfr[4];
            #pragma unroll
            for (int mi = 0; mi < 4; ++mi) {
                int r  = wm * 64 + mi * 16 + (lane & 15);
                int cb = (ks * 64 + (lane >> 4) * 16) ^ ((r & 7) << 4);
                afr[mi] = *(const bf16x8*)((const char*)Al + r * 128 + cb);
            }
            #pragma unroll
            for (int ni = 0; ni < 4; ++ni) {
                int r  = wn * 64 + ni * 16 + (lane & 15);
                int cb = (ks * 64 + (lane >> 4) * 16) ^ ((r & 7) << 4);
                bfr[ni] = *(const bf16x8*)((const char*)Bl + r * 128 + cb);
            }
            #pragma unroll
            for (int mi = 0; mi < 4; ++mi)
                #pragma unroll
                for (int ni = 0; ni < 4; ++ni)
                    acc[mi][ni] = __builtin_amdgcn_mfma_f32_16x16x32_bf16(
                        afr[mi], bfr[ni], acc[mi][ni], 0, 0, 0);
        }
        __syncthreads();
    }
    // epilogue: C row = (lane>>4)*4 + j, col = lane&15
    const int gm0 = bm + wm * 64;
    const int gn0 = bn + wn * 64 + (lane & 15);

    if (EPI == 0) {
        // z-scaled phi(Q): wave covers one full head (64 cols); 16-lane
        // butterfly gives each row its denominator.
        const int b = bm >> 13;
        const int h = (bn >> 6) + wn;
        float ksv[4];
        #pragma unroll
        for (int ni = 0; ni < 4; ++ni)
            ksv[ni] = aux[((b * 16 + h) << 6) + ni * 16 + (lane & 15)];
        #pragma unroll
        for (int mi = 0; mi < 4; ++mi) {
            #pragma unroll
            for (int j = 0; j < 4; ++j) {
                float pv[4], s = 0.0f;
                #pragma unroll
                for (int ni = 0; ni < 4; ++ni) {
                    pv[ni] = phi_f(acc[mi][ni][j]);
                    s += pv[ni] * ksv[ni];
                }
                s += __shfl_xor(s, 1);
                s += __shfl_xor(s, 2);
                s += __shfl_xor(s, 4);
                s += __shfl_xor(s, 8);
                float z = 1.0f / (s + 1e-6f);
                int gm = gm0 + mi * 16 + (lane >> 4) * 4 + j;
                __bf16* op = (__bf16*)OutV + (size_t)gm * H_ + gn0;
                #pragma unroll
                for (int ni = 0; ni < 4; ++ni)
                    op[ni * 16] = (__bf16)(pv[ni] * z);
            }
        }
    } else {
        #pragma unroll
        for (int mi = 0; mi < 4; ++mi) {
            #pragma unroll
            for (int j = 0; j < 4; ++j) {
                int gm = gm0 + mi * 16 + (lane >> 4) * 4 + j;
                if (EPI == 3) {
                    float* op = (float*)OutV + (size_t)gm * H_ + gn0;
                    #pragma unroll
                    for (int ni = 0; ni < 4; ++ni)
                        op[ni * 16] = acc[mi][ni][j];
                } else {
                    float mv = mask[gm];
                    __bf16* op = (__bf16*)OutV + (size_t)gm * H_ + gn0;
                    #pragma unroll
                    for (int ni = 0; ni < 4; ++ni) {
                        float v = acc[mi][ni][j];
                        if (EPI == 1) v = phi_f(v) * mv;
                        else          v = v * mv;
                        op[ni * 16] = (__bf16)v;
                    }
                }
            }
        }
    }
}

// ---------------------------------------------------------------------------
// KV partials via MFMA (unchanged, passing)
// ---------------------------------------------------------------------------
__global__ __launch_bounds__(256, 2)
void kv_kernel(const __bf16* __restrict__ Kb, const __bf16* __restrict__ Vb,
               float* __restrict__ KVp, float* __restrict__ Ksp)
{
    const int chunk = blockIdx.x;
    const int bh = blockIdx.y;
    const int b = bh >> 4, h = bh & 15;
    const int tid = threadIdx.x, lane = tid & 63, wid = tid >> 6;

    __shared__ char KtRaw[64 * 144];
    __shared__ char VtRaw[64 * 144];
    __shared__ float ksbuf[32][64];

    const int st  = tid >> 3;
    const int dkg = tid & 7;
    const int dk0 = dkg * 8;
    const int swzT = (dkg & 7) << 4;

    f32x4 acc[4];
    #pragma unroll
    for (int i = 0; i < 4; ++i) acc[i] = (f32x4)0.0f;
    float ksacc[8];
    #pragma unroll
    for (int i = 0; i < 8; ++i) ksacc[i] = 0.0f;

    const size_t gbase = ((size_t)b * T_ + (size_t)chunk * 1024) * H_
                         + h * 64 + dk0;

    bf16x8 ka, kc, va, vc;
    {
        const __bf16* p  = Kb + gbase;
        const __bf16* pv = Vb + gbase;
        ka = *(const bf16x8*)(p  + (size_t)st * H_);
        kc = *(const bf16x8*)(p  + (size_t)(st + 32) * H_);
        va = *(const bf16x8*)(pv + (size_t)st * H_);
        vc = *(const bf16x8*)(pv + (size_t)(st + 32) * H_);
    }

    for (int tile = 0; tile < 16; ++tile) {
        __syncthreads();
        #pragma unroll
        for (int j = 0; j < 8; ++j) {
            int rowb = (dk0 + j) * 144;
            *(__bf16*)(KtRaw + ((rowb + 2*st)        ^ swzT)) = ka[j];
            *(__bf16*)(KtRaw + ((rowb + 2*(st + 32)) ^ swzT)) = kc[j];
            *(__bf16*)(VtRaw + ((rowb + 2*st)        ^ swzT)) = va[j];
            *(__bf16*)(VtRaw + ((rowb + 2*(st + 32)) ^ swzT)) = vc[j];
            ksacc[j] += (float)ka[j] + (float)kc[j];
        }
        if (tile < 15) {
            const __bf16* p  = Kb + gbase + (size_t)(tile + 1) * 64 * H_;
            const __bf16* pv = Vb + gbase + (size_t)(tile + 1) * 64 * H_;
            ka = *(const bf16x8*)(p  + (size_t)st * H_);
            kc = *(const bf16x8*)(p  + (size_t)(st + 32) * H_);
            va = *(const bf16x8*)(pv + (size_t)st * H_);
            vc = *(const bf16x8*)(pv + (size_t)(st + 32) * H_);
        }
        __syncthreads();
        #pragma unroll
        for (int ks = 0; ks < 2; ++ks) {
            int r = wid * 16 + (lane & 15);
            int cb = (r * 144 + (ks * 64 + (lane >> 4) * 16)) ^ (((r >> 3) & 7) << 4);
            bf16x8 af = *(const bf16x8*)(KtRaw + cb);
            #pragma unroll
            for (int ni = 0; ni < 4; ++ni) {
                int rv = ni * 16 + (lane & 15);
                int cv = (rv * 144 + (ks * 64 + (lane >> 4) * 16)) ^ (((rv >> 3) & 7) << 4);
                bf16x8 bf = *(const bf16x8*)(VtRaw + cv);
                acc[ni] = __builtin_amdgcn_mfma_f32_16x16x32_bf16(af, bf, acc[ni], 0, 0, 0);
            }
        }
    }

    float* kvp = KVp + ((size_t)chunk * 64 + bh) * 4096;
    #pragma unroll
    for (int ni = 0; ni < 4; ++ni)
        #pragma unroll
        for (int jj = 0; jj < 4; ++jj) {
            int dk = wid * 16 + (lane >> 4) * 4 + jj;
            int dv = ni * 16 + (lane & 15);
            kvp[dk * 64 + dv] = acc[ni][jj];
        }

    #pragma unroll
    for (int j = 0; j < 8; ++j)
        ksbuf[st][dk0 + j] = ksacc[j];
    __syncthreads();
    if (tid < 64) {
        float s = 0.0f;
        #pragma unroll 8
        for (int st2 = 0; st2 < 32; ++st2) s += ksbuf[st2][tid];
        Ksp[((size_t)chunk * 64 + bh) * 64 + tid] = s;
    }
}

// sum 8 chunk-partials -> KVb bf16 [bh][dk][dv] (natural) + Ks fp32 [bh][dk]
__global__ void kvsum(const float* __restrict__ KVp, const float* __restrict__ Ksp,
                      __bf16* __restrict__ KVb, float* __restrict__ Ks) {
    int bh = blockIdx.x, tid = threadIdx.x;
    __bf16* d = KVb + (size_t)bh * 4096;
    for (int i = tid; i < 4096; i += 256) {
        float s = 0.0f;
        #pragma unroll
        for (int c = 0; c < 8; ++c)
            s += KVp[((size_t)c * 64 + bh) * 4096 + i];
        d[i] = (__bf16)s;
    }
    if (tid < 64) {
        float s = 0.0f;
        #pragma unroll
        for (int c = 0; c < 8; ++c)
            s += Ksp[((size_t)c * 64 + bh) * 64 + tid];
        Ks[bh * 64 + tid] = s;
    }
}

// ---------------------------------------------------------------------------
// Ut[b][m][h*64+dk] = sum_dv Wob[m][h*64+dv] * KVb[b*16+h][dk][dv]
// grid (8 m-panels, 32 b*headpair); block 256 = 4 waves (2m x 2head).
// ---------------------------------------------------------------------------
__global__ __launch_bounds__(256)
void ugemm(const __bf16* __restrict__ Wob, const __bf16* __restrict__ KVb,
           __bf16* __restrict__ Ut)
{
    const int mp = blockIdx.x, bhp = blockIdx.y;
    const int b = bhp >> 3, hp = bhp & 7;
    const int tid = threadIdx.x, lane = tid & 63, w = tid >> 6;
    const int wm = w >> 1, wn = w & 1;
    const int h = hp * 2 + wn;
    const int bm = mp * 128;
    const int lane15 = lane & 15;

    __shared__ __bf16 As[128][136];   // Wob rows, cols hp*128..+127
    __shared__ __bf16 Bs[2][64][72];  // per head [dk][dv]

    {
        int r = tid >> 1, c0 = (tid & 1) * 64;
        const __bf16* src = Wob + (size_t)(bm + r) * H_ + hp * 128 + c0;
        #pragma unroll
        for (int j = 0; j < 8; ++j)
            *(bf16x8*)&As[r][c0 + j*8] = *(const bf16x8*)(src + j*8);
    }
    {
        int hh = tid >> 7, idx = tid & 127, r = idx >> 1, c0 = (idx & 1) * 32;
        const __bf16* src = KVb + ((size_t)(b * 16 + hp * 2 + hh) * 64 + r) * 64 + c0;
        #pragma unroll
        for (int j = 0; j < 4; ++j)
            *(bf16x8*)&Bs[hh][r][c0 + j*8] = *(const bf16x8*)(src + j*8);
    }
    __syncthreads();

    f32x4 acc[4][4];
    #pragma unroll
    for (int i = 0; i < 4; ++i)
        #pragma unroll
        for (int j = 0; j < 4; ++j) acc[i][j] = (f32x4)0.0f;

    #pragma unroll
    for (int ks = 0; ks < 2; ++ks) {
        bf16x8 afr[4], bfr[4];
        #pragma unroll
        for (int mi = 0; mi < 4; ++mi)
            afr[mi] = *(const bf16x8*)&As[wm*64 + mi*16 + lane15]
                                         [wn*64 + ks*32 + (lane>>4)*8];
        #pragma unroll
        for (int ni = 0; ni < 4; ++ni)
            bfr[ni] = *(const bf16x8*)&Bs[wn][ni*16 + lane15]
                                         [ks*32 + (lane>>4)*8];
        #pragma unroll
        for (int mi = 0; mi < 4; ++mi)
            #pragma unroll
            for (int ni = 0; ni < 4; ++ni)
                acc[mi][ni] = __builtin_amdgcn_mfma_f32_16x16x32_bf16(
                    afr[mi], bfr[ni], acc[mi][ni], 0, 0, 0);
    }

    __bf16* up = Ut + ((size_t)b << 20);
    #pragma unroll
    for (int mi = 0; mi < 4; ++mi)
        #pragma unroll
        for (int j = 0; j < 4; ++j) {
            int m2 = bm + wm * 64 + mi * 16 + (lane >> 4) * 4 + j;
            #pragma unroll
            for (int ni = 0; ni < 4; ++ni) {
                int dk = ni * 16 + lane15;
                up[(size_t)m2 * H_ + h * 64 + dk] = (__bf16)acc[mi][ni][j];
            }
        }
}

// ---------------------------------------------------------------------------
extern "C" void kernel_launch(void* const* d_in, const int* in_sizes, int n_in,
                              void* d_out, int out_size, void* d_ws, size_t ws_size,
                              hipStream_t stream) {
    (void)in_sizes; (void)n_in; (void)out_size; (void)ws_size;
    const float* q    = (const float*)d_in[0];
    const float* k    = (const float*)d_in[1];
    const float* v    = (const float*)d_in[2];
    const float* mask = (const float*)d_in[3];
    const float* Wq   = (const float*)d_in[4];
    const float* Wk   = (const float*)d_in[5];
    const float* Wv   = (const float*)d_in[6];
    const float* Wo   = (const float*)d_in[7];
    float* out = (float*)d_out;

    char* ws = (char*)d_ws;
    const size_t WELEM = (size_t)H_ * H_;
    const size_t PELEM = (size_t)BT_ * H_;
    __bf16* Wqb = (__bf16*)ws;
    __bf16* Wkb = Wqb + WELEM;
    __bf16* Wvb = Wkb + WELEM;
    __bf16* Wob = Wvb + WELEM;
    __bf16* Qb  = Wob + WELEM;                 // Q' buffer
    __bf16* Kb  = Qb + PELEM;
    __bf16* Vb  = Kb + PELEM;
    __bf16* tmp = Vb + PELEM;                  // conv scratch
    float*  KVp = (float*)(tmp + PELEM);       // 8 MiB partials; reused as Ut
    float*  Ksp = KVp + (size_t)8 * 64 * 4096;
    float*  Ksf = Ksp + (size_t)8 * 64 * 64;
    __bf16* KVb = (__bf16*)(Ksf + (size_t)64 * 64);   // 64*4096 bf16
    __bf16* Ut  = (__bf16*)KVp;                // aliases dead KVp (8 MiB)

    wconv4<<<dim3(1024, 4), 256, 0, stream>>>(Wq, Wk, Wv, Wo, Wqb, Wkb, Wvb, Wob);

    const int cgrid = (int)(PELEM / (256 * 8));   // 16384
    conv_bf16<<<cgrid, 256, 0, stream>>>(k, tmp);
    gemm_bt<1><<<2048, 256, 0, stream>>>(tmp, Wkb, mask, nullptr, Kb);
    conv_bf16<<<cgrid, 256, 0, stream>>>(v, tmp);
    gemm_bt<2><<<2048, 256, 0, stream>>>(tmp, Wvb, mask, nullptr, Vb);

    kv_kernel<<<dim3(T_/1024, B_*NH_), 256, 0, stream>>>(Kb, Vb, KVp, Ksp);
    kvsum<<<B_*NH_, 256, 0, stream>>>(KVp, Ksp, KVb, Ksf);
    ugemm<<<dim3(8, 32), 256, 0, stream>>>(Wob, KVb, Ut);

    conv_bf16<<<cgrid, 256, 0, stream>>>(q, tmp);
    gemm_bt<0><<<2048, 256, 0, stream>>>(tmp, Wqb, mask, Ksf, Qb);
    gemm_bt<3><<<2048, 256, 0, stream>>>(Qb, (const __bf16*)Ut, mask, nullptr, out);
}